// Round 4
// baseline (357.230 us; speedup 1.0000x reference)
//
#include <hip/hip_runtime.h>

// ForwardForwardCountingLayer forward:
//   per (b,o): vals[i] = (et==2 ? 1-x[b,i] : x[b,i]) + (et==0 ? off : 0)
//   off = is_tnorm ? +10 : -10 ; out = is_tnorm ? min_i vals : max_i vals
// HBM-bound on the 268 MB edge_type_idx stream.
// Persistent-shaped: 2048 blocks x 4 waves, 8 rows/wave, x strip in VGPRs
// (no LDS, no syncthreads), 2-deep row pipeline (prefetch rr+1 during rr).

constexpr int B = 64;
constexpr int I = 1024;
constexpr int O = 1024;
constexpr int ROWS_PER_WAVE = 8;
constexpr int BLOCKS = (B * O) / (ROWS_PER_WAVE * 4);   // 2048

typedef int   iv4 __attribute__((ext_vector_type(4)));
typedef float fv4 __attribute__((ext_vector_type(4)));

__global__ __launch_bounds__(256) void ffcl_kernel(
    const float* __restrict__ x,       // [B, I]
    const int*   __restrict__ et,      // [B, O, I]
    const int*   __restrict__ op,      // [O]
    float*       __restrict__ out)     // [B, O]
{
    const int t    = threadIdx.x;
    const int wid  = t >> 6;
    const int lane = t & 63;
    const int wave = blockIdx.x * 4 + wid;
    const int r_base = wave * ROWS_PER_WAVE;       // rows [r_base, r_base+8), same b (8|1024)
    const int b      = r_base >> 10;
    const int o_base = r_base & (O - 1);

    // x strip for this lane: cols j*256 + lane*4, j=0..3  (16 floats in VGPRs)
    fv4 xv[4];
    #pragma unroll
    for (int j = 0; j < 4; ++j)
        xv[j] = *reinterpret_cast<const fv4*>(x + (size_t)b * I + j * 256 + lane * 4);

    // per-row op params (wave-uniform -> scalar regs)
    float sgn[ROWS_PER_WAVE], off[ROWS_PER_WAVE];
    #pragma unroll
    for (int rr = 0; rr < ROWS_PER_WAVE; ++rr) {
        const bool is_t = (op[o_base + rr] == 0);
        sgn[rr] = is_t ? -1.0f : 1.0f;             // min(v) = -max(-v); *(+-1) exact
        off[rr] = is_t ? 10.0f : -10.0f;
    }

    // et base for this lane; addr(rr, j) = pe[rr*256 + j*64]  (iv4 units)
    const iv4* pe = reinterpret_cast<const iv4*>(et + (size_t)r_base * I) + lane;

    float acc[ROWS_PER_WAVE];
    #pragma unroll
    for (int rr = 0; rr < ROWS_PER_WAVE; ++rr) acc[rr] = -3.0e38f;

    iv4 eA[4], eB[4];

#define PREFETCH(BUF, RR) { \
    _Pragma("unroll") \
    for (int j = 0; j < 4; ++j) BUF[j] = pe[(RR) * 256 + j * 64]; }

#define CONSUME(E, RR) { \
    _Pragma("unroll") \
    for (int j = 0; j < 4; ++j) { \
        float v; \
        v = (E[j].x == 2) ? 1.0f - xv[j].x : xv[j].x;  v += (E[j].x == 0) ? off[RR] : 0.0f;  acc[RR] = fmaxf(acc[RR], sgn[RR] * v); \
        v = (E[j].y == 2) ? 1.0f - xv[j].y : xv[j].y;  v += (E[j].y == 0) ? off[RR] : 0.0f;  acc[RR] = fmaxf(acc[RR], sgn[RR] * v); \
        v = (E[j].z == 2) ? 1.0f - xv[j].z : xv[j].z;  v += (E[j].z == 0) ? off[RR] : 0.0f;  acc[RR] = fmaxf(acc[RR], sgn[RR] * v); \
        v = (E[j].w == 2) ? 1.0f - xv[j].w : xv[j].w;  v += (E[j].w == 0) ? off[RR] : 0.0f;  acc[RR] = fmaxf(acc[RR], sgn[RR] * v); \
    } }

    PREFETCH(eA, 0)
    PREFETCH(eB, 1)  CONSUME(eA, 0)
    PREFETCH(eA, 2)  CONSUME(eB, 1)
    PREFETCH(eB, 3)  CONSUME(eA, 2)
    PREFETCH(eA, 4)  CONSUME(eB, 3)
    PREFETCH(eB, 5)  CONSUME(eA, 4)
    PREFETCH(eA, 6)  CONSUME(eB, 5)
    PREFETCH(eB, 7)  CONSUME(eA, 6)
                     CONSUME(eB, 7)

#undef PREFETCH
#undef CONSUME

    // one butterfly tail per 8 rows; lane rr keeps row rr's result
    float keep = 0.0f;
    #pragma unroll
    for (int rr = 0; rr < ROWS_PER_WAVE; ++rr) {
        float a = acc[rr];
        #pragma unroll
        for (int s = 32; s > 0; s >>= 1)
            a = fmaxf(a, __shfl_xor(a, s, 64));
        if (lane == rr) keep = sgn[rr] * a;
    }
    if (lane < ROWS_PER_WAVE)
        out[r_base + lane] = keep;
}

extern "C" void kernel_launch(void* const* d_in, const int* in_sizes, int n_in,
                              void* d_out, int out_size, void* d_ws, size_t ws_size,
                              hipStream_t stream) {
    const float* x   = (const float*)d_in[0];
    const int*   et  = (const int*)d_in[1];
    const int*   op  = (const int*)d_in[2];
    float*       out = (float*)d_out;

    ffcl_kernel<<<BLOCKS, 256, 0, stream>>>(x, et, op, out);
}

// Round 5
// 332.971 us; speedup vs baseline: 1.0729x; 1.0729x over previous
//
#include <hip/hip_runtime.h>

// ForwardForwardCountingLayer forward:
//   per (b,o): vals[i] = (et==2 ? 1-x[b,i] : x[b,i]) + (et==0 ? off : 0)
//   off = is_tnorm ? +10 : -10 ; out = is_tnorm ? min_i vals : max_i vals
//
// Key algebraic fact: every row has >=1 element with et!=0 (reference forces
// it), and for et!=0 the signed candidate sgn*v lies in [-1,1], while et==0
// candidates are <= -9 after sgn-folding (tnorm: -(x+10); conorm: x-10).
// So et==0 elements NEVER win the max -- replace the offset add with a
// constant -2.0 candidate. Exact (absmax 0).
//
// HBM-bound on the 268 MB et stream. Latency-limited => maximize
// (bytes in flight per wave) x (waves/CU): 4 rows/wave, ALL 16 int4 loads
// issued before any consumption (16 KB/wave), 4096 blocks, no LDS.

constexpr int B = 64;
constexpr int I = 1024;
constexpr int O = 1024;
constexpr int ROWS_PER_WAVE = 4;
constexpr int BLOCKS = (B * O) / (ROWS_PER_WAVE * 4);   // 4096

typedef int   iv4 __attribute__((ext_vector_type(4)));
typedef float fv4 __attribute__((ext_vector_type(4)));

__global__ __launch_bounds__(256) void ffcl_kernel(
    const float* __restrict__ x,       // [B, I]
    const int*   __restrict__ et,      // [B, O, I]
    const int*   __restrict__ op,      // [O]
    float*       __restrict__ out)     // [B, O]
{
    const int t      = threadIdx.x;
    const int wid    = t >> 6;
    const int lane   = t & 63;
    const int wave   = blockIdx.x * 4 + wid;
    const int r_base = wave * ROWS_PER_WAVE;       // 4 consecutive rows, same b (4|1024)
    const int b      = r_base >> 10;
    const int o_base = r_base & (O - 1);

    // et lane base; addr(rr,j) = pe[rr*256 + j*64] (iv4 units)
    const iv4* pe = reinterpret_cast<const iv4*>(et + (size_t)r_base * I) + lane;

    // Issue ALL 16 global loads first: 256 B/lane = 16 KB/wave in flight.
    iv4 e[16];
    #pragma unroll
    for (int rr = 0; rr < 4; ++rr)
        #pragma unroll
        for (int j = 0; j < 4; ++j)
            e[rr * 4 + j] = __builtin_nontemporal_load(&pe[rr * 256 + j * 64]);

    // x strip (cols j*256+lane*4) and 1-x, shared by all 4 rows: 32 VGPRs.
    fv4 xv[4], qv[4];
    #pragma unroll
    for (int j = 0; j < 4; ++j) {
        xv[j] = *reinterpret_cast<const fv4*>(x + (size_t)b * I + j * 256 + lane * 4);
        qv[j].x = 1.0f - xv[j].x;  qv[j].y = 1.0f - xv[j].y;
        qv[j].z = 1.0f - xv[j].z;  qv[j].w = 1.0f - xv[j].w;
    }

    // per-row params (wave-uniform scalar loads)
    float sgn[4];
    #pragma unroll
    for (int rr = 0; rr < 4; ++rr)
        sgn[rr] = (op[o_base + rr] == 0) ? -1.0f : 1.0f;   // min(v) = -max(-v)

    float acc[4];
    #pragma unroll
    for (int rr = 0; rr < 4; ++rr) acc[rr] = -3.0e38f;

    // candidate(e): e==0 -> -2.0 (never wins); e==2 -> sgn*(1-x); else sgn*x
    #pragma unroll
    for (int rr = 0; rr < 4; ++rr) {
        const float s = sgn[rr];
        #pragma unroll
        for (int j = 0; j < 4; ++j) {
            const iv4 ev = e[rr * 4 + j];
            float c0, c1, c2, c3;
            c0 = s * ((ev.x == 2) ? qv[j].x : xv[j].x);  c0 = (ev.x == 0) ? -2.0f : c0;
            c1 = s * ((ev.y == 2) ? qv[j].y : xv[j].y);  c1 = (ev.y == 0) ? -2.0f : c1;
            c2 = s * ((ev.z == 2) ? qv[j].z : xv[j].z);  c2 = (ev.z == 0) ? -2.0f : c2;
            c3 = s * ((ev.w == 2) ? qv[j].w : xv[j].w);  c3 = (ev.w == 0) ? -2.0f : c3;
            acc[rr] = fmaxf(fmaxf(acc[rr], c0), c1);     // clang fuses to v_max3
            acc[rr] = fmaxf(fmaxf(acc[rr], c2), c3);
        }
    }

    // one butterfly per row; lane rr keeps row rr's result
    float keep = 0.0f;
    #pragma unroll
    for (int rr = 0; rr < 4; ++rr) {
        float a = acc[rr];
        #pragma unroll
        for (int s = 32; s > 0; s >>= 1)
            a = fmaxf(a, __shfl_xor(a, s, 64));
        if (lane == rr) keep = sgn[rr] * a;
    }
    if (lane < ROWS_PER_WAVE)
        out[r_base + lane] = keep;
}

extern "C" void kernel_launch(void* const* d_in, const int* in_sizes, int n_in,
                              void* d_out, int out_size, void* d_ws, size_t ws_size,
                              hipStream_t stream) {
    const float* x   = (const float*)d_in[0];
    const int*   et  = (const int*)d_in[1];
    const int*   op  = (const int*)d_in[2];
    float*       out = (float*)d_out;

    ffcl_kernel<<<BLOCKS, 256, 0, stream>>>(x, et, op, out);
}